// Round 1
// baseline (296.253 us; speedup 1.0000x reference)
//
#include <hip/hip_runtime.h>
#include <hip/hip_bf16.h>

// Problem constants
#define M_DIM   16384     // BATCH
#define K_DIM   512       // N_FEATURES
#define NNODES  4095
#define NPAD    4096

typedef __bf16   bf16x8 __attribute__((ext_vector_type(8)));
typedef float    floatx4 __attribute__((ext_vector_type(4)));
typedef _Float16 half8  __attribute__((ext_vector_type(8)));

__device__ __forceinline__ float sigmoidf_(float z) {
    return 1.f / (1.f + __expf(-z));
}

__device__ __forceinline__ void gld_lds16(const void* g, void* l) {
    __builtin_amdgcn_global_load_lds(
        (const __attribute__((address_space(1))) void*)g,
        (__attribute__((address_space(3))) void*)l, 16, 0, 0);
}

// ---------------- fp32 -> bf16 conversion ----------------
// X: 16384x512 -> ws  (8 elems / thread, exact grid)
__global__ __launch_bounds__(256) void cvt_x(const float* __restrict__ X,
                                             __hip_bfloat16* __restrict__ Xb) {
    const int idx = (blockIdx.x * 256 + threadIdx.x) * 8;
    float4 f0 = *reinterpret_cast<const float4*>(X + idx);
    float4 f1 = *reinterpret_cast<const float4*>(X + idx + 4);
    __hip_bfloat16 h[8];
    h[0] = __float2bfloat16(f0.x); h[1] = __float2bfloat16(f0.y);
    h[2] = __float2bfloat16(f0.z); h[3] = __float2bfloat16(f0.w);
    h[4] = __float2bfloat16(f1.x); h[5] = __float2bfloat16(f1.y);
    h[6] = __float2bfloat16(f1.z); h[7] = __float2bfloat16(f1.w);
    *reinterpret_cast<int4*>(Xb + idx) = *reinterpret_cast<int4*>(h);
}

// W: 4095x512 -> padded 4096x512 bf16 (row 4095 zeroed)
__global__ __launch_bounds__(256) void cvt_w(const float* __restrict__ W,
                                             __hip_bfloat16* __restrict__ Wb) {
    const int idx = (blockIdx.x * 256 + threadIdx.x) * 8;
    const int row = idx >> 9;   // /512 (8 | 512, no row crossing)
    __hip_bfloat16 h[8];
    if (row < NNODES) {
        float4 f0 = *reinterpret_cast<const float4*>(W + idx);
        float4 f1 = *reinterpret_cast<const float4*>(W + idx + 4);
        h[0] = __float2bfloat16(f0.x); h[1] = __float2bfloat16(f0.y);
        h[2] = __float2bfloat16(f0.z); h[3] = __float2bfloat16(f0.w);
        h[4] = __float2bfloat16(f1.x); h[5] = __float2bfloat16(f1.y);
        h[6] = __float2bfloat16(f1.z); h[7] = __float2bfloat16(f1.w);
    } else {
        #pragma unroll
        for (int i = 0; i < 8; ++i) h[i] = __float2bfloat16(0.f);
    }
    *reinterpret_cast<int4*>(Wb + idx) = *reinterpret_cast<int4*>(h);
}

// ---------------- GEMM + fused sigmoid epilogue ----------------
// C[m][n] = sum_k Xb[m][k] * Wb[n][k];  p = sigmoid((C + b[n]) * s[n])
// stored fp16 at P[m*4096 + (n+1)]   (column shift for aligned fold loads)
__global__ __launch_bounds__(256) void gemm_sig(
    const __hip_bfloat16* __restrict__ A,   // [16384][512]
    const __hip_bfloat16* __restrict__ B,   // [4096][512] padded
    const float* __restrict__ bias,         // [4095]
    const float* __restrict__ scale,        // [4095]
    _Float16* __restrict__ P)               // [16384][4096]
{
    __shared__ __hip_bfloat16 lA[128 * 64];
    __shared__ __hip_bfloat16 lB[128 * 64];

    const int tid  = threadIdx.x;
    const int lane = tid & 63;
    const int wv   = tid >> 6;
    const int tile_m = blockIdx.x >> 5;     // 128 m-tiles
    const int tile_n = blockIdx.x & 31;     // 32  n-tiles
    const int m0 = tile_m * 128;
    const int n0 = tile_n * 128;

    const int wm = (wv >> 1) * 64;          // wave m offset in tile
    const int wn = (wv & 1) * 64;           // wave n offset in tile

    const int lrow = lane >> 3;             // 0..7 staging row within wave
    const int lcb  = (lane & 7) * 16;       // staging byte offset in 128B row
    const int quad = lane >> 4;             // 0..3
    const int l15  = lane & 15;

    floatx4 acc[4][4];
    #pragma unroll
    for (int i = 0; i < 4; ++i)
        #pragma unroll
        for (int j = 0; j < 4; ++j)
            acc[i][j] = (floatx4){0.f, 0.f, 0.f, 0.f};

    for (int k0 = 0; k0 < K_DIM; k0 += 64) {
        #pragma unroll
        for (int i = 0; i < 4; ++i) {
            const int rbase = i * 32 + wv * 8;            // wave-uniform
            const int row   = rbase + lrow;
            const char* gA = (const char*)(A + (size_t)(m0 + row) * K_DIM + k0) + lcb;
            const char* gB = (const char*)(B + (size_t)(n0 + row) * K_DIM + k0) + lcb;
            gld_lds16(gA, &lA[rbase * 64]);
            gld_lds16(gB, &lB[rbase * 64]);
        }
        __syncthreads();
        #pragma unroll
        for (int kk = 0; kk < 64; kk += 32) {
            bf16x8 af[4], bfr[4];
            #pragma unroll
            for (int i = 0; i < 4; ++i)
                af[i] = *reinterpret_cast<const bf16x8*>(
                    &lA[(wm + i * 16 + l15) * 64 + kk + quad * 8]);
            #pragma unroll
            for (int j = 0; j < 4; ++j)
                bfr[j] = *reinterpret_cast<const bf16x8*>(
                    &lB[(wn + j * 16 + l15) * 64 + kk + quad * 8]);
            #pragma unroll
            for (int i = 0; i < 4; ++i)
                #pragma unroll
                for (int j = 0; j < 4; ++j)
                    acc[i][j] = __builtin_amdgcn_mfma_f32_16x16x32_bf16(
                        af[i], bfr[j], acc[i][j], 0, 0, 0);
        }
        __syncthreads();
    }

    // epilogue: p = sigmoid((acc + b) * s), store fp16 at column n+1
    float bn[4], sn[4];
    int   ncol[4];
    #pragma unroll
    for (int j = 0; j < 4; ++j) {
        const int n = n0 + wn + j * 16 + l15;
        ncol[j] = n;
        bn[j] = (n < NNODES) ? bias[n]  : 0.f;
        sn[j] = (n < NNODES) ? scale[n] : 1.f;
    }
    #pragma unroll
    for (int i = 0; i < 4; ++i) {
        #pragma unroll
        for (int r = 0; r < 4; ++r) {
            const int m = m0 + wm + i * 16 + quad * 4 + r;
            _Float16* prow = P + (size_t)m * NPAD;
            #pragma unroll
            for (int j = 0; j < 4; ++j) {
                if (ncol[j] < NNODES) {
                    const float z = (acc[i][j][r] + bn[j]) * sn[j];
                    prow[ncol[j] + 1] = (_Float16)sigmoidf_(z);
                }
            }
        }
    }
}

// ---------------- tree fold ----------------
// one wave per batch row; 4 rows per 256-thread block
__global__ __launch_bounds__(256) void tree_fold(
    const _Float16* __restrict__ P,      // [16384][4096], node n at col n+1
    const float* __restrict__ leaves,    // [4096]
    float* __restrict__ out)             // [16384]
{
    __shared__ float sleaf[4096];
    __shared__ float vA[4][2048];
    __shared__ float vB[4][1024];

    const int tid = threadIdx.x;
    for (int i = tid; i < 4096; i += 256)
        sleaf[i] = sigmoidf_(leaves[i]);
    __syncthreads();

    const int lane = tid & 63;
    const int wv   = tid >> 6;
    const int b    = blockIdx.x * 4 + wv;
    const _Float16* prow = P + (size_t)b * NPAD;

    float* const vAw = vA[wv];
    float* const vBw = vB[wv];

    const float* src = sleaf;   // depth-12 "values" = sigmoid(leaves)
    float*       dst = vAw;

    // depths 11..3 vectorized: node (d,j) at column 2^d + j
    for (int d = 11; d >= 3; --d) {
        const int width = 1 << d;
        for (int j8 = lane * 8; j8 < width; j8 += 512) {
            half8 p8 = *reinterpret_cast<const half8*>(prow + width + j8);
            float4 f[4];
            const float4* sp = reinterpret_cast<const float4*>(src + 2 * j8);
            f[0] = sp[0]; f[1] = sp[1]; f[2] = sp[2]; f[3] = sp[3];
            const float* sv = reinterpret_cast<const float*>(f);
            float res[8];
            #pragma unroll
            for (int u = 0; u < 8; ++u) {
                const float p = (float)p8[u];
                res[u] = p * sv[2 * u] + (1.f - p) * sv[2 * u + 1];
            }
            *reinterpret_cast<float4*>(dst + j8)     = make_float4(res[0], res[1], res[2], res[3]);
            *reinterpret_cast<float4*>(dst + j8 + 4) = make_float4(res[4], res[5], res[6], res[7]);
        }
        const float* ns = dst;
        dst = (dst == vAw) ? vBw : vAw;
        src = ns;
    }
    // depths 2..0 scalar
    for (int d = 2; d >= 0; --d) {
        const int width = 1 << d;
        for (int j = lane; j < width; j += 64) {
            const float p = (float)prow[width + j];
            dst[j] = p * src[2 * j] + (1.f - p) * src[2 * j + 1];
        }
        const float* ns = dst;
        dst = (dst == vAw) ? vBw : vAw;
        src = ns;
    }
    if (lane == 0) out[b] = src[0];
}

// ---------------- fp32 fallback (only if workspace too small) ----------------
__global__ __launch_bounds__(256) void tnn_fallback(
    const float* __restrict__ X, const float* __restrict__ W,
    const float* __restrict__ bias, const float* __restrict__ scale,
    const float* __restrict__ leaves, float* __restrict__ out)
{
    __shared__ float xr[512];
    __shared__ float sl[4096];
    __shared__ float pp[4096];
    __shared__ float v0[2048];
    __shared__ float v1[1024];
    const int tid  = threadIdx.x;
    const int lane = tid & 63;
    const int wv   = tid >> 6;
    const int b    = blockIdx.x;
    for (int i = tid; i < 512;  i += 256) xr[i] = X[(size_t)b * 512 + i];
    for (int i = tid; i < 4096; i += 256) sl[i] = sigmoidf_(leaves[i]);
    __syncthreads();
    for (int n = wv; n < NNODES; n += 4) {
        float sum = 0.f;
        const float* wr = W + (size_t)n * 512;
        for (int k = lane; k < 512; k += 64) sum += xr[k] * wr[k];
        #pragma unroll
        for (int off = 32; off; off >>= 1) sum += __shfl_xor(sum, off);
        if (lane == 0) pp[n] = sigmoidf_((sum + bias[n]) * scale[n]);
    }
    __syncthreads();
    for (int j = tid; j < 2048; j += 256) {
        const float p = pp[2047 + j];
        v0[j] = p * sl[2 * j] + (1.f - p) * sl[2 * j + 1];
    }
    __syncthreads();
    float* src = v0;
    float* dst = v1;
    for (int d = 10; d >= 0; --d) {
        const int width = 1 << d;
        const int start = width - 1;
        for (int j = tid; j < width; j += 256) {
            const float p = pp[start + j];
            dst[j] = p * src[2 * j] + (1.f - p) * src[2 * j + 1];
        }
        __syncthreads();
        float* t = src; src = dst; dst = t;
    }
    if (tid == 0) out[b] = src[0];
}

extern "C" void kernel_launch(void* const* d_in, const int* in_sizes, int n_in,
                              void* d_out, int out_size, void* d_ws, size_t ws_size,
                              hipStream_t stream) {
    const float* X      = (const float*)d_in[0];
    const float* W      = (const float*)d_in[1];
    const float* bias   = (const float*)d_in[2];
    const float* scale  = (const float*)d_in[3];
    const float* leaves = (const float*)d_in[4];
    float* out = (float*)d_out;

    const size_t offX = 0;
    const size_t offW = (size_t)M_DIM * K_DIM * 2;                 // 16 MB
    const size_t offP = offW + (size_t)NPAD * K_DIM * 2;           // +4 MB
    const size_t need = offP + (size_t)M_DIM * NPAD * 2;           // +128 MB

    if (ws_size >= need) {
        __hip_bfloat16* Xb = (__hip_bfloat16*)((char*)d_ws + offX);
        __hip_bfloat16* Wb = (__hip_bfloat16*)((char*)d_ws + offW);
        _Float16*       P  = (_Float16*)((char*)d_ws + offP);
        cvt_x<<<(M_DIM * K_DIM) / (256 * 8), 256, 0, stream>>>(X, Xb);
        cvt_w<<<((size_t)NPAD * K_DIM) / (256 * 8), 256, 0, stream>>>(W, Wb);
        gemm_sig<<<(M_DIM / 128) * (NPAD / 128), 256, 0, stream>>>(Xb, Wb, bias, scale, P);
        tree_fold<<<M_DIM / 4, 256, 0, stream>>>(P, leaves, out);
    } else {
        tnn_fallback<<<M_DIM, 256, 0, stream>>>(X, W, bias, scale, leaves, out);
    }
}

// Round 2
// 247.912 us; speedup vs baseline: 1.1950x; 1.1950x over previous
//
#include <hip/hip_runtime.h>
#include <hip/hip_bf16.h>

// Problem constants
#define M_DIM   16384     // BATCH
#define K_DIM   512       // N_FEATURES
#define NNODES  4095
#define NPERM   4096      // permuted bottom-subtree columns (128 subtrees x 32)
#define NTOP    128       // top nodes 0..126 + 1 pad
#define NWROWS  (NPERM + NTOP)

typedef __bf16   bf16x8 __attribute__((ext_vector_type(8)));
typedef float    floatx4 __attribute__((ext_vector_type(4)));

__device__ __forceinline__ float sigmoidf_(float z) {
    return 1.f / (1.f + __expf(-z));
}

__device__ __forceinline__ void gld_lds16(const void* g, void* l) {
    __builtin_amdgcn_global_load_lds(
        (const __attribute__((address_space(1))) void*)g,
        (__attribute__((address_space(3))) void*)l, 16, 0, 0);
}

// ---------------- fp32 -> bf16 conversion ----------------
// X: 16384x512 -> ws  (8 elems / thread, exact grid)
__global__ __launch_bounds__(256) void cvt_x(const float* __restrict__ X,
                                             __hip_bfloat16* __restrict__ Xb) {
    const int idx = (blockIdx.x * 256 + threadIdx.x) * 8;
    float4 f0 = *reinterpret_cast<const float4*>(X + idx);
    float4 f1 = *reinterpret_cast<const float4*>(X + idx + 4);
    __hip_bfloat16 h[8];
    h[0] = __float2bfloat16(f0.x); h[1] = __float2bfloat16(f0.y);
    h[2] = __float2bfloat16(f0.z); h[3] = __float2bfloat16(f0.w);
    h[4] = __float2bfloat16(f1.x); h[5] = __float2bfloat16(f1.y);
    h[6] = __float2bfloat16(f1.z); h[7] = __float2bfloat16(f1.w);
    *reinterpret_cast<int4*>(Xb + idx) = *reinterpret_cast<int4*>(h);
}

// W: 4095x512 fp32 -> permuted/padded 4224x512 bf16, plus permuted bias/scale.
// Rows 0..4095: subtree t = r>>5, slot o = r&31:
//   o in [0,16): depth-11 node q=o; [16,24): d10 q=o-16; [24,28): d9; [28,30): d8;
//   o==30: d7 root; o==31: pad. Global node = 2^d-1 + (t << (d-7)) + q.
// Rows 4096..4223: top node c = r-4096 (c<127), else pad.
__global__ __launch_bounds__(256) void cvt_w(const float* __restrict__ W,
                                             const float* __restrict__ bias,
                                             const float* __restrict__ scale,
                                             __hip_bfloat16* __restrict__ Wb,
                                             float* __restrict__ bp,
                                             float* __restrict__ sp) {
    const int idx = (blockIdx.x * 256 + threadIdx.x) * 8;
    const int r = idx >> 9;
    const int k = idx & 511;
    int node;
    if (r < NPERM) {
        const int t = r >> 5, o = r & 31;
        int d, q;
        if (o < 16)       { d = 11; q = o; }
        else if (o < 24)  { d = 10; q = o - 16; }
        else if (o < 28)  { d = 9;  q = o - 24; }
        else if (o < 30)  { d = 8;  q = o - 28; }
        else if (o == 30) { d = 7;  q = 0; }
        else              { d = -1; q = 0; }
        node = (d < 0) ? -1 : ((1 << d) - 1 + (t << (d - 7)) + q);
    } else {
        const int c = r - NPERM;
        node = (c < 127) ? c : -1;
    }
    __hip_bfloat16 h[8];
    if (node >= 0) {
        const float* src = W + (size_t)node * 512 + k;
        float4 f0 = *reinterpret_cast<const float4*>(src);
        float4 f1 = *reinterpret_cast<const float4*>(src + 4);
        h[0] = __float2bfloat16(f0.x); h[1] = __float2bfloat16(f0.y);
        h[2] = __float2bfloat16(f0.z); h[3] = __float2bfloat16(f0.w);
        h[4] = __float2bfloat16(f1.x); h[5] = __float2bfloat16(f1.y);
        h[6] = __float2bfloat16(f1.z); h[7] = __float2bfloat16(f1.w);
    } else {
        #pragma unroll
        for (int i = 0; i < 8; ++i) h[i] = __float2bfloat16(0.f);
    }
    *reinterpret_cast<int4*>(Wb + idx) = *reinterpret_cast<int4*>(h);
    if (k == 0) {
        bp[r] = (node >= 0) ? bias[node]  : 0.f;
        sp[r] = (node >= 0) ? scale[node] : 1.f;
    }
}

// ---------------- GEMM + sigmoid + bottom-5-level tree fold ----------------
// Block: 128 rows x 128 cols (= 4 subtrees). Emits partial[row][subtree] fp32.
#define PT_STRIDE 132   // halves; 264B/row -> 2-bank shift/row, conflict-free fold
__global__ __launch_bounds__(256) void gemm_fold(
    const __hip_bfloat16* __restrict__ A,   // [16384][512]
    const __hip_bfloat16* __restrict__ B,   // [4224][512] permuted
    const float* __restrict__ bp,           // [4224]
    const float* __restrict__ sp,           // [4224]
    const float* __restrict__ leaves,       // [4096]
    float* __restrict__ partial)            // [16384][128]
{
    __shared__ char smem[34304] __attribute__((aligned(16)));
    __hip_bfloat16* lA = (__hip_bfloat16*)smem;           // 16 KB (GEMM phase)
    __hip_bfloat16* lB = lA + 8192;                       // 16 KB (GEMM phase)
    _Float16* pt  = (_Float16*)smem;                      // 128*132 halves (epilogue)
    float*    slf = (float*)(smem + 33792);               // 128 sigmoid(leaves)

    const int tid  = threadIdx.x;
    const int lane = tid & 63;
    const int wv   = tid >> 6;
    const int tile_m = blockIdx.x >> 5;     // 128 m-tiles
    const int tile_n = blockIdx.x & 31;     // 32  n-tiles (4 subtrees each)
    const int m0 = tile_m * 128;
    const int n0 = tile_n * 128;

    // sigmoid(leaves) for this block's 4 subtrees (region doesn't alias lA/lB)
    if (tid < 128) slf[tid] = sigmoidf_(leaves[n0 + tid]);

    const int wm = (wv >> 1) * 64;
    const int wn = (wv & 1) * 64;
    const int lrow = lane >> 3;
    const int lcb  = (lane & 7) * 16;
    const int quad = lane >> 4;
    const int l15  = lane & 15;

    floatx4 acc[4][4];
    #pragma unroll
    for (int i = 0; i < 4; ++i)
        #pragma unroll
        for (int j = 0; j < 4; ++j)
            acc[i][j] = (floatx4){0.f, 0.f, 0.f, 0.f};

    for (int k0 = 0; k0 < K_DIM; k0 += 64) {
        #pragma unroll
        for (int i = 0; i < 4; ++i) {
            const int rbase = i * 32 + wv * 8;
            const int row   = rbase + lrow;
            const char* gA = (const char*)(A + (size_t)(m0 + row) * K_DIM + k0) + lcb;
            const char* gB = (const char*)(B + (size_t)(n0 + row) * K_DIM + k0) + lcb;
            gld_lds16(gA, &lA[rbase * 64]);
            gld_lds16(gB, &lB[rbase * 64]);
        }
        __syncthreads();
        #pragma unroll
        for (int kk = 0; kk < 64; kk += 32) {
            bf16x8 af[4], bfr[4];
            #pragma unroll
            for (int i = 0; i < 4; ++i)
                af[i] = *reinterpret_cast<const bf16x8*>(
                    &lA[(wm + i * 16 + l15) * 64 + kk + quad * 8]);
            #pragma unroll
            for (int j = 0; j < 4; ++j)
                bfr[j] = *reinterpret_cast<const bf16x8*>(
                    &lB[(wn + j * 16 + l15) * 64 + kk + quad * 8]);
            #pragma unroll
            for (int i = 0; i < 4; ++i)
                #pragma unroll
                for (int j = 0; j < 4; ++j)
                    acc[i][j] = __builtin_amdgcn_mfma_f32_16x16x32_bf16(
                        af[i], bfr[j], acc[i][j], 0, 0, 0);
        }
        __syncthreads();
    }

    // ---- epilogue: p = sigmoid((acc+b)*s) -> LDS (fp16), then subtree fold ----
    float bn[4], sn[4];
    #pragma unroll
    for (int j = 0; j < 4; ++j) {
        const int n = n0 + wn + j * 16 + l15;   // < 4096 always; pads give p=0.5 (unused)
        bn[j] = bp[n];
        sn[j] = sp[n];
    }
    #pragma unroll
    for (int i = 0; i < 4; ++i) {
        #pragma unroll
        for (int r = 0; r < 4; ++r) {
            const int row = wm + i * 16 + quad * 4 + r;
            #pragma unroll
            for (int j = 0; j < 4; ++j) {
                const int col = wn + j * 16 + l15;
                pt[row * PT_STRIDE + col] =
                    (_Float16)sigmoidf_((acc[i][j][r] + bn[j]) * sn[j]);
            }
        }
    }
    __syncthreads();

    // 512 tasks (128 rows x 4 subtrees), 2 per thread
    #pragma unroll
    for (int z = 0; z < 2; ++z) {
        const int task = tid + z * 256;
        const int row  = task >> 2;
        const int t    = task & 3;
        const _Float16* pp = pt + row * PT_STRIDE + t * 32;
        const float*    sl = slf + t * 32;
        float v[16];
        #pragma unroll
        for (int q = 0; q < 16; ++q) {
            const float p = (float)pp[q];
            v[q] = p * sl[2 * q] + (1.f - p) * sl[2 * q + 1];
        }
        #pragma unroll
        for (int q = 0; q < 8; ++q) {
            const float p = (float)pp[16 + q];
            v[q] = p * v[2 * q] + (1.f - p) * v[2 * q + 1];
        }
        #pragma unroll
        for (int q = 0; q < 4; ++q) {
            const float p = (float)pp[24 + q];
            v[q] = p * v[2 * q] + (1.f - p) * v[2 * q + 1];
        }
        #pragma unroll
        for (int q = 0; q < 2; ++q) {
            const float p = (float)pp[28 + q];
            v[q] = p * v[2 * q] + (1.f - p) * v[2 * q + 1];
        }
        const float p7 = (float)pp[30];
        partial[(size_t)(m0 + row) * 128 + tile_n * 4 + t] =
            p7 * v[0] + (1.f - p7) * v[1];
    }
}

// ---------------- top-7-level GEMM + fold ----------------
// 128 blocks; block = 128 rows x 128 cols (nodes 0..126 + pad).
#define PL_STRIDE 129   // floats; 1-bank shift/row -> conflict-free per-row fold
__global__ __launch_bounds__(256) void fold_top(
    const __hip_bfloat16* __restrict__ A,    // [16384][512]
    const __hip_bfloat16* __restrict__ B2,   // [128][512] (top nodes, permuted tail)
    const float* __restrict__ bp2,           // [128]
    const float* __restrict__ sp2,           // [128]
    const float* __restrict__ partial,       // [16384][128]
    float* __restrict__ out)                 // [16384]
{
    __shared__ char smem[99840] __attribute__((aligned(16)));
    __hip_bfloat16* lA = (__hip_bfloat16*)smem;           // GEMM phase
    __hip_bfloat16* lB = lA + 8192;
    _Float16* pt = (_Float16*)smem;                       // 128*132 halves
    float*    pL = (float*)(smem + 33792);                // 128*129 floats

    const int tid  = threadIdx.x;
    const int lane = tid & 63;
    const int wv   = tid >> 6;
    const int m0   = blockIdx.x * 128;

    const int wm = (wv >> 1) * 64;
    const int wn = (wv & 1) * 64;
    const int lrow = lane >> 3;
    const int lcb  = (lane & 7) * 16;
    const int quad = lane >> 4;
    const int l15  = lane & 15;

    floatx4 acc[4][4];
    #pragma unroll
    for (int i = 0; i < 4; ++i)
        #pragma unroll
        for (int j = 0; j < 4; ++j)
            acc[i][j] = (floatx4){0.f, 0.f, 0.f, 0.f};

    for (int k0 = 0; k0 < K_DIM; k0 += 64) {
        #pragma unroll
        for (int i = 0; i < 4; ++i) {
            const int rbase = i * 32 + wv * 8;
            const int row   = rbase + lrow;
            const char* gA = (const char*)(A + (size_t)(m0 + row) * K_DIM + k0) + lcb;
            const char* gB = (const char*)(B2 + (size_t)row * K_DIM + k0) + lcb;
            gld_lds16(gA, &lA[rbase * 64]);
            gld_lds16(gB, &lB[rbase * 64]);
        }
        __syncthreads();
        #pragma unroll
        for (int kk = 0; kk < 64; kk += 32) {
            bf16x8 af[4], bfr[4];
            #pragma unroll
            for (int i = 0; i < 4; ++i)
                af[i] = *reinterpret_cast<const bf16x8*>(
                    &lA[(wm + i * 16 + l15) * 64 + kk + quad * 8]);
            #pragma unroll
            for (int j = 0; j < 4; ++j)
                bfr[j] = *reinterpret_cast<const bf16x8*>(
                    &lB[(wn + j * 16 + l15) * 64 + kk + quad * 8]);
            #pragma unroll
            for (int i = 0; i < 4; ++i)
                #pragma unroll
                for (int j = 0; j < 4; ++j)
                    acc[i][j] = __builtin_amdgcn_mfma_f32_16x16x32_bf16(
                        af[i], bfr[j], acc[i][j], 0, 0, 0);
        }
        __syncthreads();
    }

    // p-tile to LDS
    float bn[4], sn[4];
    #pragma unroll
    for (int j = 0; j < 4; ++j) {
        const int n = wn + j * 16 + l15;
        bn[j] = bp2[n];
        sn[j] = sp2[n];
    }
    #pragma unroll
    for (int i = 0; i < 4; ++i) {
        #pragma unroll
        for (int r = 0; r < 4; ++r) {
            const int row = wm + i * 16 + quad * 4 + r;
            #pragma unroll
            for (int j = 0; j < 4; ++j) {
                const int col = wn + j * 16 + l15;
                pt[row * PT_STRIDE + col] =
                    (_Float16)sigmoidf_((acc[i][j][r] + bn[j]) * sn[j]);
            }
        }
    }
    // stage partial tile into LDS (can't alias pt -- separate region)
    for (int it = 0; it < 64; ++it) {
        const int idx = tid + it * 256;
        const int row = idx >> 7;
        const int c   = idx & 127;
        pL[row * PL_STRIDE + c] = partial[(size_t)(m0 + row) * 128 + c];
    }
    __syncthreads();

    // per-row serial fold over top 7 levels (threads 0..127)
    if (tid < 128) {
        float* v = pL + tid * PL_STRIDE;
        const _Float16* pr = pt + tid * PT_STRIDE;
        #pragma unroll
        for (int d = 6; d >= 1; --d) {
            const int base = (1 << d) - 1;
            const int cnt  = 1 << d;
            for (int q = 0; q < cnt; ++q) {
                const float p = (float)pr[base + q];
                v[q] = p * v[2 * q] + (1.f - p) * v[2 * q + 1];
            }
        }
        const float p0 = (float)pr[0];
        out[m0 + tid] = p0 * v[0] + (1.f - p0) * v[1];
    }
}

// ---------------- fp32 fallback (only if workspace too small) ----------------
__global__ __launch_bounds__(256) void tnn_fallback(
    const float* __restrict__ X, const float* __restrict__ W,
    const float* __restrict__ bias, const float* __restrict__ scale,
    const float* __restrict__ leaves, float* __restrict__ out)
{
    __shared__ float xr[512];
    __shared__ float sl[4096];
    __shared__ float pp[4096];
    __shared__ float v0[2048];
    __shared__ float v1[1024];
    const int tid  = threadIdx.x;
    const int lane = tid & 63;
    const int wv   = tid >> 6;
    const int b    = blockIdx.x;
    for (int i = tid; i < 512;  i += 256) xr[i] = X[(size_t)b * 512 + i];
    for (int i = tid; i < 4096; i += 256) sl[i] = sigmoidf_(leaves[i]);
    __syncthreads();
    for (int n = wv; n < NNODES; n += 4) {
        float sum = 0.f;
        const float* wr = W + (size_t)n * 512;
        for (int k = lane; k < 512; k += 64) sum += xr[k] * wr[k];
        #pragma unroll
        for (int off = 32; off; off >>= 1) sum += __shfl_xor(sum, off);
        if (lane == 0) pp[n] = sigmoidf_((sum + bias[n]) * scale[n]);
    }
    __syncthreads();
    for (int j = tid; j < 2048; j += 256) {
        const float p = pp[2047 + j];
        v0[j] = p * sl[2 * j] + (1.f - p) * sl[2 * j + 1];
    }
    __syncthreads();
    float* src = v0;
    float* dst = v1;
    for (int d = 10; d >= 0; --d) {
        const int width = 1 << d;
        const int start = width - 1;
        for (int j = tid; j < width; j += 256) {
            const float p = pp[start + j];
            dst[j] = p * src[2 * j] + (1.f - p) * src[2 * j + 1];
        }
        __syncthreads();
        float* t = src; src = dst; dst = t;
    }
    if (tid == 0) out[b] = src[0];
}

extern "C" void kernel_launch(void* const* d_in, const int* in_sizes, int n_in,
                              void* d_out, int out_size, void* d_ws, size_t ws_size,
                              hipStream_t stream) {
    const float* X      = (const float*)d_in[0];
    const float* W      = (const float*)d_in[1];
    const float* bias   = (const float*)d_in[2];
    const float* scale  = (const float*)d_in[3];
    const float* leaves = (const float*)d_in[4];
    float* out = (float*)d_out;

    const size_t offX  = 0;
    const size_t offW  = (size_t)M_DIM * K_DIM * 2;                 // 16 MB
    const size_t offB  = offW + (size_t)NWROWS * K_DIM * 2;         // +4.125 MB
    const size_t offS  = offB + (size_t)NWROWS * 4;
    const size_t offP  = offS + (size_t)NWROWS * 4;
    const size_t need  = offP + (size_t)M_DIM * 128 * 4;            // +8 MB

    if (ws_size >= need) {
        __hip_bfloat16* Xb = (__hip_bfloat16*)((char*)d_ws + offX);
        __hip_bfloat16* Wb = (__hip_bfloat16*)((char*)d_ws + offW);
        float* bp = (float*)((char*)d_ws + offB);
        float* sp = (float*)((char*)d_ws + offS);
        float* partial = (float*)((char*)d_ws + offP);
        cvt_x<<<(M_DIM * K_DIM) / (256 * 8), 256, 0, stream>>>(X, Xb);
        cvt_w<<<((size_t)NWROWS * K_DIM) / (256 * 8), 256, 0, stream>>>(
            W, bias, scale, Wb, bp, sp);
        gemm_fold<<<(M_DIM / 128) * (NPERM / 128), 256, 0, stream>>>(
            Xb, Wb, bp, sp, leaves, partial);
        fold_top<<<M_DIM / 128, 256, 0, stream>>>(
            Xb, Wb + (size_t)NPERM * K_DIM, bp + NPERM, sp + NPERM, partial, out);
    } else {
        tnn_fallback<<<M_DIM, 256, 0, stream>>>(X, W, bias, scale, leaves, out);
    }
}

// Round 3
// 244.149 us; speedup vs baseline: 1.2134x; 1.0154x over previous
//
#include <hip/hip_runtime.h>
#include <hip/hip_bf16.h>

// Problem constants
#define M_DIM   16384     // BATCH
#define K_DIM   512       // N_FEATURES
#define NNODES  4095
#define NPERM   4096      // permuted bottom-subtree columns (128 subtrees x 32)
#define NTOP    128       // top nodes 0..126 + 1 pad
#define NWROWS  (NPERM + NTOP)
#define NTILES  33        // 32 bottom n-tiles + 1 top tile

typedef __bf16   bf16x8 __attribute__((ext_vector_type(8)));
typedef float    floatx4 __attribute__((ext_vector_type(4)));

// 4-inst sigmoid: v_mul(v_exp scale), v_exp, v_add, v_rcp. Rel err ~1e-7, fine
// vs 1.06e-2 threshold (we're at 3.9e-3 with the exact divide).
__device__ __forceinline__ float sigmoidf_(float z) {
    return __builtin_amdgcn_rcpf(1.f + __expf(-z));
}

__device__ __forceinline__ void gld_lds16(const void* g, void* l) {
    __builtin_amdgcn_global_load_lds(
        (const __attribute__((address_space(1))) void*)g,
        (__attribute__((address_space(3))) void*)l, 16, 0, 0);
}

// ---------------- fp32 -> bf16 conversion ----------------
__global__ __launch_bounds__(256) void cvt_x(const float* __restrict__ X,
                                             __hip_bfloat16* __restrict__ Xb) {
    const int idx = (blockIdx.x * 256 + threadIdx.x) * 8;
    float4 f0 = *reinterpret_cast<const float4*>(X + idx);
    float4 f1 = *reinterpret_cast<const float4*>(X + idx + 4);
    __hip_bfloat16 h[8];
    h[0] = __float2bfloat16(f0.x); h[1] = __float2bfloat16(f0.y);
    h[2] = __float2bfloat16(f0.z); h[3] = __float2bfloat16(f0.w);
    h[4] = __float2bfloat16(f1.x); h[5] = __float2bfloat16(f1.y);
    h[6] = __float2bfloat16(f1.z); h[7] = __float2bfloat16(f1.w);
    *reinterpret_cast<int4*>(Xb + idx) = *reinterpret_cast<int4*>(h);
}

// W: 4095x512 fp32 -> permuted/padded 4224x512 bf16, plus permuted bias/scale.
// Rows 0..4095: subtree t = r>>5, slot o = r&31:
//   o in [0,16): d11 q=o; [16,24): d10; [24,28): d9; [28,30): d8; 30: d7 root;
//   31: pad. Global node = 2^d-1 + (t << (d-7)) + q.
// Rows 4096..4223: top node c = r-4096 (c<127), else pad.
__global__ __launch_bounds__(256) void cvt_w(const float* __restrict__ W,
                                             const float* __restrict__ bias,
                                             const float* __restrict__ scale,
                                             __hip_bfloat16* __restrict__ Wb,
                                             float* __restrict__ bp,
                                             float* __restrict__ sp) {
    const int idx = (blockIdx.x * 256 + threadIdx.x) * 8;
    const int r = idx >> 9;
    const int k = idx & 511;
    int node;
    if (r < NPERM) {
        const int t = r >> 5, o = r & 31;
        int d, q;
        if (o < 16)       { d = 11; q = o; }
        else if (o < 24)  { d = 10; q = o - 16; }
        else if (o < 28)  { d = 9;  q = o - 24; }
        else if (o < 30)  { d = 8;  q = o - 28; }
        else if (o == 30) { d = 7;  q = 0; }
        else              { d = -1; q = 0; }
        node = (d < 0) ? -1 : ((1 << d) - 1 + (t << (d - 7)) + q);
    } else {
        const int c = r - NPERM;
        node = (c < 127) ? c : -1;
    }
    __hip_bfloat16 h[8];
    if (node >= 0) {
        const float* src = W + (size_t)node * 512 + k;
        float4 f0 = *reinterpret_cast<const float4*>(src);
        float4 f1 = *reinterpret_cast<const float4*>(src + 4);
        h[0] = __float2bfloat16(f0.x); h[1] = __float2bfloat16(f0.y);
        h[2] = __float2bfloat16(f0.z); h[3] = __float2bfloat16(f0.w);
        h[4] = __float2bfloat16(f1.x); h[5] = __float2bfloat16(f1.y);
        h[6] = __float2bfloat16(f1.z); h[7] = __float2bfloat16(f1.w);
    } else {
        #pragma unroll
        for (int i = 0; i < 8; ++i) h[i] = __float2bfloat16(0.f);
    }
    *reinterpret_cast<int4*>(Wb + idx) = *reinterpret_cast<int4*>(h);
    if (k == 0) {
        bp[r] = (node >= 0) ? bias[node]  : 0.f;
        sp[r] = (node >= 0) ? scale[node] : 1.f;
    }
}

// ---------------- GEMM + sigmoid + bottom-5-level tree fold ----------------
// grid (33, 128): tile_n = blockIdx.x (32==top nodes), tile_m = blockIdx.y.
// tile_n<32: emits partial[row][subtree] fp32.  tile_n==32: emits ptop fp16.
#define PT_STRIDE 134   // halves; 268 B/row = odd dword stride -> fold reads 2-way max
__global__ __launch_bounds__(256) void gemm_fold(
    const __hip_bfloat16* __restrict__ A,   // [16384][512]
    const __hip_bfloat16* __restrict__ B,   // [4224][512] permuted
    const float* __restrict__ bp,           // [4224]
    const float* __restrict__ sp,           // [4224]
    const float* __restrict__ leaves,       // [4096]
    float* __restrict__ partial,            // [16384][128]
    _Float16* __restrict__ ptop)            // [16384][128]
{
    __shared__ char smem[34816] __attribute__((aligned(16)));
    __hip_bfloat16* lA = (__hip_bfloat16*)smem;           // 16 KB (GEMM phase)
    __hip_bfloat16* lB = lA + 8192;                       // 16 KB (GEMM phase)
    _Float16* pt  = (_Float16*)smem;                      // 128*134 halves (epilogue)
    float*    slf = (float*)(smem + 34304);               // 128 sigmoid(leaves)

    const int tid  = threadIdx.x;
    const int lane = tid & 63;
    const int wv   = tid >> 6;
    const int tile_n = blockIdx.x;
    const int tile_m = blockIdx.y;
    const int m0 = tile_m * 128;
    const int n0 = tile_n * 128;

    if (tile_n < 32 && tid < 128) slf[tid] = sigmoidf_(leaves[n0 + tid]);

    const int wm = (wv >> 1) * 64;
    const int wn = (wv & 1) * 64;
    const int lrow = lane >> 3;
    const int lcb  = (lane & 7) * 16;
    const int quad = lane >> 4;
    const int l15  = lane & 15;

    // hoisted staging pointers (incremented by 128 B per k-iter)
    const char* gAp[4];
    const char* gBp[4];
    #pragma unroll
    for (int i = 0; i < 4; ++i) {
        const int rbase = i * 32 + wv * 8;
        gAp[i] = (const char*)(A + (size_t)(m0 + rbase + lrow) * K_DIM) + lcb;
        gBp[i] = (const char*)(B + (size_t)(n0 + rbase + lrow) * K_DIM) + lcb;
    }

    floatx4 acc[4][4];
    #pragma unroll
    for (int i = 0; i < 4; ++i)
        #pragma unroll
        for (int j = 0; j < 4; ++j)
            acc[i][j] = (floatx4){0.f, 0.f, 0.f, 0.f};

    #pragma unroll 1
    for (int k0 = 0; k0 < K_DIM; k0 += 64) {
        #pragma unroll
        for (int i = 0; i < 4; ++i) {
            const int rbase = i * 32 + wv * 8;
            gld_lds16(gAp[i], &lA[rbase * 64]);
            gld_lds16(gBp[i], &lB[rbase * 64]);
            gAp[i] += 128; gBp[i] += 128;
        }
        __syncthreads();
        #pragma unroll
        for (int kk = 0; kk < 64; kk += 32) {
            bf16x8 af[4], bfr[4];
            #pragma unroll
            for (int i = 0; i < 4; ++i)
                af[i] = *reinterpret_cast<const bf16x8*>(
                    &lA[(wm + i * 16 + l15) * 64 + kk + quad * 8]);
            #pragma unroll
            for (int j = 0; j < 4; ++j)
                bfr[j] = *reinterpret_cast<const bf16x8*>(
                    &lB[(wn + j * 16 + l15) * 64 + kk + quad * 8]);
            #pragma unroll
            for (int i = 0; i < 4; ++i)
                #pragma unroll
                for (int j = 0; j < 4; ++j)
                    acc[i][j] = __builtin_amdgcn_mfma_f32_16x16x32_bf16(
                        af[i], bfr[j], acc[i][j], 0, 0, 0);
        }
        __syncthreads();
    }

    float bn[4], sn[4];
    #pragma unroll
    for (int j = 0; j < 4; ++j) {
        const int n = n0 + wn + j * 16 + l15;
        bn[j] = bp[n];
        sn[j] = sp[n];
    }

    if (tile_n == 32) {
        // top-node tile: p straight to global (no fold)
        #pragma unroll
        for (int i = 0; i < 4; ++i) {
            #pragma unroll
            for (int r = 0; r < 4; ++r) {
                const int m = m0 + wm + i * 16 + quad * 4 + r;
                #pragma unroll
                for (int j = 0; j < 4; ++j) {
                    const int col = wn + j * 16 + l15;
                    ptop[(size_t)m * 128 + col] =
                        (_Float16)sigmoidf_((acc[i][j][r] + bn[j]) * sn[j]);
                }
            }
        }
        return;
    }

    // p -> LDS (fp16), then per-subtree fold
    #pragma unroll
    for (int i = 0; i < 4; ++i) {
        #pragma unroll
        for (int r = 0; r < 4; ++r) {
            const int row = wm + i * 16 + quad * 4 + r;
            #pragma unroll
            for (int j = 0; j < 4; ++j) {
                const int col = wn + j * 16 + l15;
                pt[row * PT_STRIDE + col] =
                    (_Float16)sigmoidf_((acc[i][j][r] + bn[j]) * sn[j]);
            }
        }
    }
    __syncthreads();

    // 512 tasks (128 rows x 4 subtrees), 2 per thread
    #pragma unroll
    for (int z = 0; z < 2; ++z) {
        const int task = tid + z * 256;
        const int row  = task >> 2;
        const int t    = task & 3;
        const _Float16* pp = pt + row * PT_STRIDE + t * 32;
        const float*    sl = slf + t * 32;
        float v[16];
        #pragma unroll
        for (int q = 0; q < 16; ++q) {
            const float p = (float)pp[q];
            v[q] = p * sl[2 * q] + (1.f - p) * sl[2 * q + 1];
        }
        #pragma unroll
        for (int q = 0; q < 8; ++q) {
            const float p = (float)pp[16 + q];
            v[q] = p * v[2 * q] + (1.f - p) * v[2 * q + 1];
        }
        #pragma unroll
        for (int q = 0; q < 4; ++q) {
            const float p = (float)pp[24 + q];
            v[q] = p * v[2 * q] + (1.f - p) * v[2 * q + 1];
        }
        #pragma unroll
        for (int q = 0; q < 2; ++q) {
            const float p = (float)pp[28 + q];
            v[q] = p * v[2 * q] + (1.f - p) * v[2 * q + 1];
        }
        const float p7 = (float)pp[30];
        partial[(size_t)(m0 + row) * 128 + tile_n * 4 + t] =
            p7 * v[0] + (1.f - p7) * v[1];
    }
}

// ---------------- final top-7-level fold ----------------
// 256 blocks x 64 rows. Reads partial (8 MB) + ptop (4 MB); ~12 MB total.
__global__ __launch_bounds__(256) void final_fold(
    const float* __restrict__ partial,       // [16384][128]
    const _Float16* __restrict__ ptop,       // [16384][128], node c at col c
    float* __restrict__ out)                 // [16384]
{
    __shared__ float    pL[64 * 129];        // odd dword stride: conflict-free
    __shared__ _Float16 pq[64 * 134];

    const int tid = threadIdx.x;
    const int m0  = blockIdx.x * 64;

    #pragma unroll
    for (int it = 0; it < 32; ++it) {
        const int idx = tid + it * 256;      // 8192 = 64*128
        const int row = idx >> 7;
        const int c   = idx & 127;
        pL[row * 129 + c] = partial[(size_t)(m0 + row) * 128 + c];
        pq[row * 134 + c] = ptop[(size_t)(m0 + row) * 128 + c];
    }
    __syncthreads();

    if (tid < 64) {
        float* v = pL + tid * 129;
        const _Float16* pr = pq + tid * 134;
        #pragma unroll
        for (int d = 6; d >= 1; --d) {
            const int base = (1 << d) - 1;
            const int cnt  = 1 << d;
            for (int q = 0; q < cnt; ++q) {
                const float p = (float)pr[base + q];
                v[q] = p * v[2 * q] + (1.f - p) * v[2 * q + 1];
            }
        }
        const float p0 = (float)pr[0];
        out[m0 + tid] = p0 * v[0] + (1.f - p0) * v[1];
    }
}

// ---------------- fp32 fallback (only if workspace too small) ----------------
__global__ __launch_bounds__(256) void tnn_fallback(
    const float* __restrict__ X, const float* __restrict__ W,
    const float* __restrict__ bias, const float* __restrict__ scale,
    const float* __restrict__ leaves, float* __restrict__ out)
{
    __shared__ float xr[512];
    __shared__ float sl[4096];
    __shared__ float pp[4096];
    __shared__ float v0[2048];
    __shared__ float v1[1024];
    const int tid  = threadIdx.x;
    const int lane = tid & 63;
    const int wv   = tid >> 6;
    const int b    = blockIdx.x;
    for (int i = tid; i < 512;  i += 256) xr[i] = X[(size_t)b * 512 + i];
    for (int i = tid; i < 4096; i += 256) sl[i] = sigmoidf_(leaves[i]);
    __syncthreads();
    for (int n = wv; n < NNODES; n += 4) {
        float sum = 0.f;
        const float* wr = W + (size_t)n * 512;
        for (int k = lane; k < 512; k += 64) sum += xr[k] * wr[k];
        #pragma unroll
        for (int off = 32; off; off >>= 1) sum += __shfl_xor(sum, off);
        if (lane == 0) pp[n] = sigmoidf_((sum + bias[n]) * scale[n]);
    }
    __syncthreads();
    for (int j = tid; j < 2048; j += 256) {
        const float p = pp[2047 + j];
        v0[j] = p * sl[2 * j] + (1.f - p) * sl[2 * j + 1];
    }
    __syncthreads();
    float* src = v0;
    float* dst = v1;
    for (int d = 10; d >= 0; --d) {
        const int width = 1 << d;
        const int start = width - 1;
        for (int j = tid; j < width; j += 256) {
            const float p = pp[start + j];
            dst[j] = p * src[2 * j] + (1.f - p) * src[2 * j + 1];
        }
        __syncthreads();
        float* t = src; src = dst; dst = t;
    }
    if (tid == 0) out[b] = src[0];
}

extern "C" void kernel_launch(void* const* d_in, const int* in_sizes, int n_in,
                              void* d_out, int out_size, void* d_ws, size_t ws_size,
                              hipStream_t stream) {
    const float* X      = (const float*)d_in[0];
    const float* W      = (const float*)d_in[1];
    const float* bias   = (const float*)d_in[2];
    const float* scale  = (const float*)d_in[3];
    const float* leaves = (const float*)d_in[4];
    float* out = (float*)d_out;

    const size_t offX  = 0;
    const size_t offW  = (size_t)M_DIM * K_DIM * 2;                 // 16 MB
    const size_t offB  = offW + (size_t)NWROWS * K_DIM * 2;         // +4.125 MB
    const size_t offS  = offB + (size_t)NWROWS * 4;
    const size_t offP  = offS + (size_t)NWROWS * 4;
    const size_t offT  = offP + (size_t)M_DIM * 128 * 4;            // +8 MB
    const size_t need  = offT + (size_t)M_DIM * 128 * 2;            // +4 MB

    if (ws_size >= need) {
        __hip_bfloat16* Xb = (__hip_bfloat16*)((char*)d_ws + offX);
        __hip_bfloat16* Wb = (__hip_bfloat16*)((char*)d_ws + offW);
        float* bp = (float*)((char*)d_ws + offB);
        float* sp = (float*)((char*)d_ws + offS);
        float* partial = (float*)((char*)d_ws + offP);
        _Float16* ptop = (_Float16*)((char*)d_ws + offT);
        cvt_x<<<(M_DIM * K_DIM) / (256 * 8), 256, 0, stream>>>(X, Xb);
        cvt_w<<<((size_t)NWROWS * K_DIM) / (256 * 8), 256, 0, stream>>>(
            W, bias, scale, Wb, bp, sp);
        gemm_fold<<<dim3(NTILES, M_DIM / 128), 256, 0, stream>>>(
            Xb, Wb, bp, sp, leaves, partial, ptop);
        final_fold<<<M_DIM / 64, 256, 0, stream>>>(partial, ptop, out);
    } else {
        tnn_fallback<<<M_DIM, 256, 0, stream>>>(X, W, bias, scale, leaves, out);
    }
}